// Round 9
// baseline (100.123 us; speedup 1.0000x reference)
//
#include <hip/hip_runtime.h>

#define TPB 256

typedef __attribute__((ext_vector_type(8))) short bf16x8;    // 8 bf16 = 4 VGPRs
typedef __attribute__((ext_vector_type(16))) float f32x16;   // 32x32 accumulator

__device__ inline unsigned short f2bf(float f) {             // RNE fp32->bf16
    unsigned u = __float_as_uint(f);
    return (unsigned short)((u + 0x7FFFu + ((u >> 16) & 1u)) >> 16);
}
__device__ inline float bf2f(unsigned short h) {
    return __uint_as_float((unsigned)h << 16);
}
__device__ inline uint4 pack8(unsigned short s0, unsigned short s1,
                              unsigned short s2, unsigned short s3,
                              unsigned short s4, unsigned short s5,
                              unsigned short s6, unsigned short s7) {
    uint4 v;
    v.x = (unsigned)s0 | ((unsigned)s1 << 16);
    v.y = (unsigned)s2 | ((unsigned)s3 << 16);
    v.z = (unsigned)s4 | ((unsigned)s5 << 16);
    v.w = (unsigned)s6 | ((unsigned)s7 << 16);
    return v;
}
__device__ inline bf16x8 as_frag(uint4 v) {
    union { uint4 u; bf16x8 f; } c; c.u = v; return c.f;
}

// FULL-DISTANCE pack (R8-verified, absmax 0.0): MFMA emits the complete
// D = |p|^2 + |t|^2 - 2 p.t.  K=16 slots (same slot convention both sides):
//   0-2: ah.th   3-5: al.th   6-8: ah.tl   9-11: |p|^2(3-split).1
//   12-14: 1.|t|^2(3-split)   15: 0        (al.tl dropped, ~4e-6 RMS)
// EVERY point gets both an A-format (row side) and B-format (col side) pack,
// so both chamfer directions run from the same prep.
__global__ __launch_bounds__(TPB) void prep_kernel(
        const float* __restrict__ a, const float* __restrict__ b,
        uint4* __restrict__ pAa, uint4* __restrict__ pBa,   // pred rows / pred cols
        uint4* __restrict__ pAt, uint4* __restrict__ pBt,   // targ rows / targ cols
        unsigned* __restrict__ pmins,
        float* __restrict__ acc, unsigned* __restrict__ cnt, int n) {
    int idx = blockIdx.x * TPB + threadIdx.x;
    const unsigned short ONE = 0x3F80;
    if (idx < 2 * n) {
        int isT = idx >= n;
        int i = isT ? idx - n : idx;
        const float* s = isT ? b : a;
        float x = s[3 * i], y = s[3 * i + 1], z = s[3 * i + 2];
        float w = x * x + y * y + z * z;
        // A side: hi/lo split of -2*coords
        float ax = -2.0f * x, ay = -2.0f * y, az = -2.0f * z;
        unsigned short ahx = f2bf(ax), ahy = f2bf(ay), ahz = f2bf(az);
        unsigned short alx = f2bf(ax - bf2f(ahx));
        unsigned short aly = f2bf(ay - bf2f(ahy));
        unsigned short alz = f2bf(az - bf2f(ahz));
        // B side: hi/lo split of coords
        unsigned short thx = f2bf(x), thy = f2bf(y), thz = f2bf(z);
        unsigned short tlx = f2bf(x - bf2f(thx));
        unsigned short tly = f2bf(y - bf2f(thy));
        unsigned short tlz = f2bf(z - bf2f(thz));
        // |.|^2 3-split (~24 significand bits)
        unsigned short wh = f2bf(w);  float r1 = w - bf2f(wh);
        unsigned short wm = f2bf(r1); float r2 = r1 - bf2f(wm);
        unsigned short wl = f2bf(r2);
        uint4* Ad = (isT ? pAt : pAa) + (size_t)i * 2;
        uint4* Bd = (isT ? pBt : pBa) + (size_t)i * 2;
        Ad[0] = pack8(ahx, ahy, ahz, alx, aly, alz, ahx, ahy);
        Ad[1] = pack8(ahz, wh, wm, wl, ONE, ONE, ONE, 0);
        Bd[0] = pack8(thx, thy, thz, thx, thy, thz, tlx, tly);
        Bd[1] = pack8(tlz, ONE, ONE, ONE, wh, wm, wl, 0);
        pmins[idx] = 0xFFFFFFFFu;
    }
    if (idx == 0) { acc[0] = 0.0f; cnt[0] = 0u; }
}

// Barrier-free streaming minpass, min3-paired fold at 3 waves/SIMD.
//
// R8's fusion null proved minpass is NOT MFMA/traffic-bound: it is fold-VALU
// + latency exposure at occupancy 2.  This round attacks both:
//  - PAIR iteration: 2 B-tiles -> FOUR fresh d-tiles (no R4 WAR reuse),
//    folded rm = fminf(rm, fminf(dX,dY)) -> backend min3 combine emits
//    v_min3_f32 (no inline asm -- R6's MFMA-hazard lesson).  32 min3 per
//    4096 pairs = half of R7's fold VALU.
//  - __launch_bounds__(256,3): 170-reg budget; live set ~148 (d 64 + rm 32
//    + a 8 + P 16 + z 16-in-AGPR + addr) fits -> 3 blocks/CU co-resident.
// Block = 4 waves x 64 rows = 256 rows; TS=8 (2048-target slice);
// grid = 2*64*8 = 1024.  B read global->reg, rotating 4-tile prefetch.
// L2 locality note: with TS=8 the default bid%8 XCD mapping puts all 64
// same-slice blocks on one XCD -> the 64 KB slice is XCD-L2-resident.
__global__ __launch_bounds__(TPB, 3) void minpass_kernel(
        const uint4* __restrict__ pAa, const uint4* __restrict__ pBa,
        const uint4* __restrict__ pAt, const uint4* __restrict__ pBt,
        unsigned* __restrict__ pmins, int n) {
    const int TS = 8;
    const int NRB = n / 256;          // 64 row-blocks (256 rows each)
    const int TGT = n / TS;           // 2048 targets per slice
    const int NP = TGT / 64;          // 32 pair-iterations (2 tiles each)

    int bid = blockIdx.x;
    int dir = bid / (NRB * TS);
    int rem = bid % (NRB * TS);
    int rbk = rem / TS;
    int ts  = rem % TS;

    const uint4* __restrict__ Ap = dir ? pAt : pAa;   // rows
    const uint4* __restrict__ Bp = dir ? pBa : pBt;   // cols

    const int tid = threadIdx.x;
    const int wid = tid >> 6, lane = tid & 63;
    const int lr = lane & 31, lh = lane >> 5;

    const int rowbase = rbk * 256 + wid * 64;
    bf16x8 a0 = as_frag(Ap[(size_t)(rowbase + lr) * 2 + lh]);
    bf16x8 a1 = as_frag(Ap[(size_t)(rowbase + 32 + lr) * 2 + lh]);

    float rm0[16], rm1[16];
#pragma unroll
    for (int i = 0; i < 16; ++i) { rm0[i] = __builtin_inff(); rm1[i] = __builtin_inff(); }
    f32x16 z = {};   // zero C operand

    // lane's B-frag pointer: 32-target tile t at uint4-offset t*64; the
    // wave's 64 lanes cover a contiguous 1KB segment (coalesced dwordx4).
    const uint4* __restrict__ bp = Bp + (size_t)(ts * TGT + lr) * 2 + lh;

    // Pair iteration: all 4 MFMAs issue into FRESH d-tiles, then the folds.
#define PAIR_ITER(B0, B1) do {                                                  \
    bf16x8 b0 = as_frag(B0), b1 = as_frag(B1);                                  \
    f32x16 d00 = __builtin_amdgcn_mfma_f32_32x32x16_bf16(a0, b0, z, 0, 0, 0);   \
    f32x16 d01 = __builtin_amdgcn_mfma_f32_32x32x16_bf16(a0, b1, z, 0, 0, 0);   \
    f32x16 d10 = __builtin_amdgcn_mfma_f32_32x32x16_bf16(a1, b0, z, 0, 0, 0);   \
    f32x16 d11 = __builtin_amdgcn_mfma_f32_32x32x16_bf16(a1, b1, z, 0, 0, 0);   \
    _Pragma("unroll")                                                           \
    for (int i = 0; i < 16; ++i) {                                              \
        rm0[i] = fminf(rm0[i], fminf(d00[i], d01[i]));   /* -> v_min3 */        \
        rm1[i] = fminf(rm1[i], fminf(d10[i], d11[i]));   /* -> v_min3 */        \
    }                                                                           \
} while (0)

    // rotating 4-tile (2-pair-iter) prefetch
    uint4 P0 = bp[0], P1 = bp[64], P2 = bp[128], P3 = bp[192];
    for (int p = 0; p + 4 <= NP; p += 2) {
        PAIR_ITER(P0, P1);
        P0 = bp[(size_t)(2 * p + 4) * 64];
        P1 = bp[(size_t)(2 * p + 5) * 64];
        PAIR_ITER(P2, P3);
        P2 = bp[(size_t)(2 * p + 6) * 64];
        P3 = bp[(size_t)(2 * p + 7) * 64];
    }
    PAIR_ITER(P0, P1);   // pair-iters NP-2, NP-1
    PAIR_ITER(P2, P3);
#undef PAIR_ITER

    // row-min fold over the 32 columns held by this lane-half
#pragma unroll
    for (int k = 1; k < 32; k <<= 1) {
#pragma unroll
        for (int i = 0; i < 16; ++i) {
            rm0[i] = fminf(rm0[i], __shfl_xor(rm0[i], k, 64));
            rm1[i] = fminf(rm1[i], __shfl_xor(rm1[i], k, 64));
        }
    }
    if (lr == 0) {   // lanes 0 and 32: rows (i&3)+8*(i>>2)+4*lh (+32 for a1)
        unsigned* pm = pmins + (size_t)dir * n;
        int rb0 = rowbase + lh * 4;
#pragma unroll
        for (int i = 0; i < 16; ++i) {
            int r = (i & 3) + ((i >> 2) << 3);
            // full distance already (nonneg) -> uint-monotone atomicMin
            atomicMin(&pm[rb0 + r], __float_as_uint(rm0[i]));
            atomicMin(&pm[rb0 + 32 + r], __float_as_uint(rm1[i]));
        }
    }
}

__global__ __launch_bounds__(TPB) void finalize_kernel(
        const uint4* __restrict__ pmins, float* __restrict__ acc,
        unsigned* __restrict__ cnt, float* __restrict__ out, int n, int nblocks) {
    int i = blockIdx.x * TPB + threadIdx.x;
    uint4 v = pmins[i];
    float sum = __uint_as_float(v.x) + __uint_as_float(v.y)
              + __uint_as_float(v.z) + __uint_as_float(v.w);
    for (int off = 32; off > 0; off >>= 1)
        sum += __shfl_down(sum, off, 64);
    __shared__ float wsum[TPB / 64];
    int lane = threadIdx.x & 63, wid = threadIdx.x >> 6;
    if (lane == 0) wsum[wid] = sum;
    __syncthreads();
    if (threadIdx.x == 0) {
        float t = 0.0f;
        for (int w = 0; w < TPB / 64; ++w) t += wsum[w];
        atomicAdd(acc, t);
        __threadfence();
        unsigned old = atomicAdd(cnt, 1u);
        if (old == (unsigned)(nblocks - 1)) {
            float a0 = atomicAdd(acc, 0.0f);
            out[0] = a0 / (float)(2 * n);
        }
    }
}

extern "C" void kernel_launch(void* const* d_in, const int* in_sizes, int n_in,
                              void* d_out, int out_size, void* d_ws, size_t ws_size,
                              hipStream_t stream) {
    const float* a = (const float*)d_in[0];
    const float* b = (const float*)d_in[1];
    int n = in_sizes[0] / 3;  // 16384
    float* out = (float*)d_out;
    char* ws = (char*)d_ws;
    float* acc = (float*)ws;                       // 1 float
    unsigned* cnt = (unsigned*)(ws + 8);           // 1 uint
    char* packs = ws + 256;
    size_t psz = (size_t)n * 32;                   // 512 KB per pack
    uint4* pAa = (uint4*)(packs);                  // pred rows (A-fmt)
    uint4* pBa = (uint4*)(packs + psz);            // pred cols (B-fmt)
    uint4* pAt = (uint4*)(packs + 2 * psz);        // targ rows (A-fmt)
    uint4* pBt = (uint4*)(packs + 3 * psz);        // targ cols (B-fmt)
    unsigned* pmins = (unsigned*)(packs + 4 * psz);

    prep_kernel<<<(2 * n + TPB - 1) / TPB, TPB, 0, stream>>>(
        a, b, pAa, pBa, pAt, pBt, pmins, acc, cnt, n);
    int mblocks = 2 * (n / 256) * 8;               // 1024
    minpass_kernel<<<mblocks, TPB, 0, stream>>>(
        pAa, pBa, pAt, pBt, pmins, n);
    int fblocks = (2 * n / 4) / TPB;               // 32
    finalize_kernel<<<fblocks, TPB, 0, stream>>>(
        (const uint4*)pmins, acc, cnt, out, n, fblocks);
}

// Round 10
// 80.083 us; speedup vs baseline: 1.2503x; 1.2503x over previous
//
#include <hip/hip_runtime.h>

#define TPB 256

typedef __attribute__((ext_vector_type(8))) short bf16x8;    // 8 bf16 = 4 VGPRs
typedef __attribute__((ext_vector_type(16))) float f32x16;   // 32x32 accumulator

__device__ inline unsigned short f2bf(float f) {             // RNE fp32->bf16
    unsigned u = __float_as_uint(f);
    return (unsigned short)((u + 0x7FFFu + ((u >> 16) & 1u)) >> 16);
}
__device__ inline float bf2f(unsigned short h) {
    return __uint_as_float((unsigned)h << 16);
}
__device__ inline uint4 pack8(unsigned short s0, unsigned short s1,
                              unsigned short s2, unsigned short s3,
                              unsigned short s4, unsigned short s5,
                              unsigned short s6, unsigned short s7) {
    uint4 v;
    v.x = (unsigned)s0 | ((unsigned)s1 << 16);
    v.y = (unsigned)s2 | ((unsigned)s3 << 16);
    v.z = (unsigned)s4 | ((unsigned)s5 << 16);
    v.w = (unsigned)s6 | ((unsigned)s7 << 16);
    return v;
}
__device__ inline bf16x8 as_frag(uint4 v) {
    union { uint4 u; bf16x8 f; } c; c.u = v; return c.f;
}

// FULL-DISTANCE pack (R8/R9-verified, absmax 0.0): MFMA emits the complete
// D = |p|^2 + |t|^2 - 2 p.t.  K=16 slots (same slot convention both sides):
//   0-2: ah.th   3-5: al.th   6-8: ah.tl   9-11: |p|^2(3-split).1
//   12-14: 1.|t|^2(3-split)   15: 0        (al.tl dropped, ~4e-6 RMS)
// Every point gets both an A-format (row side) and B-format (col side) pack.
__global__ __launch_bounds__(TPB) void prep_kernel(
        const float* __restrict__ a, const float* __restrict__ b,
        uint4* __restrict__ pAa, uint4* __restrict__ pBa,   // pred rows / pred cols
        uint4* __restrict__ pAt, uint4* __restrict__ pBt,   // targ rows / targ cols
        unsigned* __restrict__ pmins,
        float* __restrict__ acc, unsigned* __restrict__ cnt, int n) {
    int idx = blockIdx.x * TPB + threadIdx.x;
    const unsigned short ONE = 0x3F80;
    if (idx < 2 * n) {
        int isT = idx >= n;
        int i = isT ? idx - n : idx;
        const float* s = isT ? b : a;
        float x = s[3 * i], y = s[3 * i + 1], z = s[3 * i + 2];
        float w = x * x + y * y + z * z;
        float ax = -2.0f * x, ay = -2.0f * y, az = -2.0f * z;
        unsigned short ahx = f2bf(ax), ahy = f2bf(ay), ahz = f2bf(az);
        unsigned short alx = f2bf(ax - bf2f(ahx));
        unsigned short aly = f2bf(ay - bf2f(ahy));
        unsigned short alz = f2bf(az - bf2f(ahz));
        unsigned short thx = f2bf(x), thy = f2bf(y), thz = f2bf(z);
        unsigned short tlx = f2bf(x - bf2f(thx));
        unsigned short tly = f2bf(y - bf2f(thy));
        unsigned short tlz = f2bf(z - bf2f(thz));
        unsigned short wh = f2bf(w);  float r1 = w - bf2f(wh);
        unsigned short wm = f2bf(r1); float r2 = r1 - bf2f(wm);
        unsigned short wl = f2bf(r2);
        uint4* Ad = (isT ? pAt : pAa) + (size_t)i * 2;
        uint4* Bd = (isT ? pBt : pBa) + (size_t)i * 2;
        Ad[0] = pack8(ahx, ahy, ahz, alx, aly, alz, ahx, ahy);
        Ad[1] = pack8(ahz, wh, wm, wl, ONE, ONE, ONE, 0);
        Bd[0] = pack8(thx, thy, thz, thx, thy, thz, tlx, tly);
        Bd[1] = pack8(tlz, ONE, ONE, ONE, wh, wm, wl, 0);
        pmins[idx] = 0xFFFFFFFFu;
    }
    if (idx == 0) { acc[0] = 0.0f; cnt[0] = 0u; }
}

// Barrier-free streaming minpass = R7's proven shape (2 fresh d-tiles, fminf
// fold, (256,2) budget -- the only register-stable config across R1-R9)
// with ONE change: prefetch depth 4 -> 8.
//
// R9 post-mortem: 4-concurrent-d-tile variants (R1/R4/R9) all blow the
// unified register file (arch/AGPR split, occupancy collapse) -> dead lever.
// R3/R7's ~31 us vs the ~8 us issue floor is ~75% wait: the 4-deep rotation
// issues each B-load only ~3 tiles (~220 cyc) before use vs ~200-500 cyc L2
// load-use latency -> per-tile vmcnt stall.  8 rotating prefetch registers
// (32 VGPRs, fits easily in the 2-wave budget) push load->use distance to
// 7 tiles (~560 issue-cyc): steady-state stall ~0, loads never drained
// (T4 lesson: keep the pipeline deep, never vmcnt(0) mid-loop).
// Block = 4 waves x 64 rows = 256 rows; TS=4 (4096-target slice, 128 tiles);
// grid = 2*64*4 = 512 = 2 blocks/CU.
__global__ __launch_bounds__(TPB, 2) void minpass_kernel(
        const uint4* __restrict__ pAa, const uint4* __restrict__ pBa,
        const uint4* __restrict__ pAt, const uint4* __restrict__ pBt,
        unsigned* __restrict__ pmins, int n) {
    const int TS = 4;
    const int NRB = n / 256;          // 64 row-blocks (256 rows each)
    const int TGT = n / TS;           // 4096 targets per slice
    const int NT = TGT / 32;          // 128 B-tiles per wave

    int bid = blockIdx.x;
    int dir = bid / (NRB * TS);
    int rem = bid % (NRB * TS);
    int rbk = rem / TS;
    int ts  = rem % TS;

    const uint4* __restrict__ Ap = dir ? pAt : pAa;   // rows
    const uint4* __restrict__ Bp = dir ? pBa : pBt;   // cols

    const int tid = threadIdx.x;
    const int wid = tid >> 6, lane = tid & 63;
    const int lr = lane & 31, lh = lane >> 5;

    const int rowbase = rbk * 256 + wid * 64;
    bf16x8 a0 = as_frag(Ap[(size_t)(rowbase + lr) * 2 + lh]);
    bf16x8 a1 = as_frag(Ap[(size_t)(rowbase + 32 + lr) * 2 + lh]);

    float rm0[16], rm1[16];
#pragma unroll
    for (int i = 0; i < 16; ++i) { rm0[i] = __builtin_inff(); rm1[i] = __builtin_inff(); }
    f32x16 z = {};   // zero C operand

    // lane's B-frag pointer: 32-target tile t at uint4-offset t*64; the
    // wave's 64 lanes cover a contiguous 1KB segment (coalesced dwordx4).
    const uint4* __restrict__ bp = Bp + (size_t)(ts * TGT + lr) * 2 + lh;

#define COMPUTE_TILE(X) do {                                                   \
    bf16x8 bb = as_frag(X);                                                    \
    f32x16 d0 = __builtin_amdgcn_mfma_f32_32x32x16_bf16(a0, bb, z, 0, 0, 0);   \
    f32x16 d1 = __builtin_amdgcn_mfma_f32_32x32x16_bf16(a1, bb, z, 0, 0, 0);   \
    _Pragma("unroll")                                                          \
    for (int i = 0; i < 16; ++i) {                                             \
        rm0[i] = fminf(rm0[i], d0[i]);                                         \
        rm1[i] = fminf(rm1[i], d1[i]);                                         \
    }                                                                          \
} while (0)

    // 8-deep rotating prefetch: load->use distance = 7 tiles (~560 issue-cyc)
    uint4 P0 = bp[0],       P1 = bp[64],      P2 = bp[2 * 64], P3 = bp[3 * 64];
    uint4 P4 = bp[4 * 64],  P5 = bp[5 * 64],  P6 = bp[6 * 64], P7 = bp[7 * 64];
    for (int t = 0; t + 8 < NT; t += 8) {
        COMPUTE_TILE(P0); P0 = bp[(size_t)(t +  8) * 64];
        COMPUTE_TILE(P1); P1 = bp[(size_t)(t +  9) * 64];
        COMPUTE_TILE(P2); P2 = bp[(size_t)(t + 10) * 64];
        COMPUTE_TILE(P3); P3 = bp[(size_t)(t + 11) * 64];
        COMPUTE_TILE(P4); P4 = bp[(size_t)(t + 12) * 64];
        COMPUTE_TILE(P5); P5 = bp[(size_t)(t + 13) * 64];
        COMPUTE_TILE(P6); P6 = bp[(size_t)(t + 14) * 64];
        COMPUTE_TILE(P7); P7 = bp[(size_t)(t + 15) * 64];
    }
    COMPUTE_TILE(P0); COMPUTE_TILE(P1); COMPUTE_TILE(P2); COMPUTE_TILE(P3);
    COMPUTE_TILE(P4); COMPUTE_TILE(P5); COMPUTE_TILE(P6); COMPUTE_TILE(P7);
#undef COMPUTE_TILE

    // row-min fold over the 32 columns held by this lane-half
#pragma unroll
    for (int k = 1; k < 32; k <<= 1) {
#pragma unroll
        for (int i = 0; i < 16; ++i) {
            rm0[i] = fminf(rm0[i], __shfl_xor(rm0[i], k, 64));
            rm1[i] = fminf(rm1[i], __shfl_xor(rm1[i], k, 64));
        }
    }
    if (lr == 0) {   // lanes 0 and 32: rows (i&3)+8*(i>>2)+4*lh (+32 for a1)
        unsigned* pm = pmins + (size_t)dir * n;
        int rb0 = rowbase + lh * 4;
#pragma unroll
        for (int i = 0; i < 16; ++i) {
            int r = (i & 3) + ((i >> 2) << 3);
            // full distance already (nonneg) -> uint-monotone atomicMin
            atomicMin(&pm[rb0 + r], __float_as_uint(rm0[i]));
            atomicMin(&pm[rb0 + 32 + r], __float_as_uint(rm1[i]));
        }
    }
}

__global__ __launch_bounds__(TPB) void finalize_kernel(
        const uint4* __restrict__ pmins, float* __restrict__ acc,
        unsigned* __restrict__ cnt, float* __restrict__ out, int n, int nblocks) {
    int i = blockIdx.x * TPB + threadIdx.x;
    uint4 v = pmins[i];
    float sum = __uint_as_float(v.x) + __uint_as_float(v.y)
              + __uint_as_float(v.z) + __uint_as_float(v.w);
    for (int off = 32; off > 0; off >>= 1)
        sum += __shfl_down(sum, off, 64);
    __shared__ float wsum[TPB / 64];
    int lane = threadIdx.x & 63, wid = threadIdx.x >> 6;
    if (lane == 0) wsum[wid] = sum;
    __syncthreads();
    if (threadIdx.x == 0) {
        float t = 0.0f;
        for (int w = 0; w < TPB / 64; ++w) t += wsum[w];
        atomicAdd(acc, t);
        __threadfence();
        unsigned old = atomicAdd(cnt, 1u);
        if (old == (unsigned)(nblocks - 1)) {
            float a0 = atomicAdd(acc, 0.0f);
            out[0] = a0 / (float)(2 * n);
        }
    }
}

extern "C" void kernel_launch(void* const* d_in, const int* in_sizes, int n_in,
                              void* d_out, int out_size, void* d_ws, size_t ws_size,
                              hipStream_t stream) {
    const float* a = (const float*)d_in[0];
    const float* b = (const float*)d_in[1];
    int n = in_sizes[0] / 3;  // 16384
    float* out = (float*)d_out;
    char* ws = (char*)d_ws;
    float* acc = (float*)ws;                       // 1 float
    unsigned* cnt = (unsigned*)(ws + 8);           // 1 uint
    char* packs = ws + 256;
    size_t psz = (size_t)n * 32;                   // 512 KB per pack
    uint4* pAa = (uint4*)(packs);                  // pred rows (A-fmt)
    uint4* pBa = (uint4*)(packs + psz);            // pred cols (B-fmt)
    uint4* pAt = (uint4*)(packs + 2 * psz);        // targ rows (A-fmt)
    uint4* pBt = (uint4*)(packs + 3 * psz);        // targ cols (B-fmt)
    unsigned* pmins = (unsigned*)(packs + 4 * psz);

    prep_kernel<<<(2 * n + TPB - 1) / TPB, TPB, 0, stream>>>(
        a, b, pAa, pBa, pAt, pBt, pmins, acc, cnt, n);
    int mblocks = 2 * (n / 256) * 4;               // 512 = 2 blocks/CU
    minpass_kernel<<<mblocks, TPB, 0, stream>>>(
        pAa, pBa, pAt, pBt, pmins, n);
    int fblocks = (2 * n / 4) / TPB;               // 32
    finalize_kernel<<<fblocks, TPB, 0, stream>>>(
        (const uint4*)pmins, acc, cnt, out, n, fblocks);
}